// Round 1
// baseline (210.298 us; speedup 1.0000x reference)
//
#include <hip/hip_runtime.h>
#include <hip/hip_bf16.h>

// Dilated-mask attention, B=2 H=16 S=2048 D=64, dilation=2.
// mask[i,j]=1 iff i,j same parity; masked scores are EXACTLY 0 (multiplicative
// mask), softmax over all 2048 -> flash attention over same-parity keys with
// init m=0 and final correction  out += exp(-m)*Vsum_otherparity,
// Z = l + 1024*exp(-m).

#define B_   2
#define H_   16
#define S_   2048
#define D_   64
#define SP_  1024          // keys per parity
#define BQ   64            // queries per block (one parity)
#define BK   64            // keys per tile
#define NKT  (SP_ / BK)    // 16 tiles
#define LSTR 72            // LDS row stride in bf16 (144 B = 9*16 B aligned, conflict-free b128)

typedef __bf16 bf16x8 __attribute__((ext_vector_type(8)));
typedef float  f32x4  __attribute__((ext_vector_type(4)));

// ---------------- Vsum precompute: vsum[bh][parity][d] = sum_j V[bh][j][d] over parity j
__global__ __launch_bounds__(1024) void vsum_kernel(const float* __restrict__ V,
                                                    float* __restrict__ vsum) {
    const int bh   = blockIdx.x;
    const int tid  = threadIdx.x;
    const int lane = tid & 63;     // = d
    const int w    = tid >> 6;     // 16 waves, 128 rows each
    const float* Vb = V + (size_t)bh * S_ * D_;
    float se = 0.f, so = 0.f;
    const int r0 = w * 128;        // even
    for (int i = 0; i < 128; i += 2) {
        se += Vb[(size_t)(r0 + i)     * D_ + lane];
        so += Vb[(size_t)(r0 + i + 1) * D_ + lane];
    }
    __shared__ float red[2][16][64];
    red[0][w][lane] = se;
    red[1][w][lane] = so;
    __syncthreads();
    if (tid < 128) {
        const int p = tid >> 6, d = tid & 63;
        float s = 0.f;
        #pragma unroll
        for (int j = 0; j < 16; ++j) s += red[p][j][d];
        vsum[((size_t)bh * 2 + p) * D_ + d] = s;
    }
}

// ---------------- Main flash-attention kernel
__global__ __launch_bounds__(256, 3) void attn_kernel(const float* __restrict__ Q,
                                                      const float* __restrict__ K,
                                                      const float* __restrict__ V,
                                                      const float* __restrict__ vsum,
                                                      float* __restrict__ out) {
    // grid (bh=32, par=2, qt=16): q-tiles of one (bh,par) differ by 64 in linear
    // block id -> same XCD under %8 round-robin -> K/V L2 reuse.
    const int bh  = blockIdx.x;
    const int par = blockIdx.y;
    const int qt  = blockIdx.z;
    const int tid  = threadIdx.x;
    const int lane = tid & 63;
    const int wave = tid >> 6;      // 4 waves; wave w owns query rows [16w,16w+16)
    const int l15  = lane & 15;
    const int quad = lane >> 4;

    __shared__ __align__(16) __bf16 q_s[BQ][LSTR];
    __shared__ __align__(16) __bf16 k_s[BK][LSTR];
    __shared__ __align__(16) __bf16 vhi_s[D_][LSTR];   // V^T, bf16 high part
    __shared__ __align__(16) __bf16 vlo_s[D_][LSTR];   // V^T, bf16 residual
    __shared__ __align__(16) __bf16 p_s[4][16][LSTR];  // per-wave P strip

    const size_t base = (size_t)bh * S_ * D_;
    const float* Qb = Q + base;
    const float* Kb = K + base;
    const float* Vb = V + base;

    // ---- stage Q tile (rows par + 2*(qt*64 + r)), fp32 -> bf16
    #pragma unroll
    for (int i = 0; i < 4; ++i) {
        const int f = (i << 8) + tid;          // float4 index 0..1023
        const int r = f >> 4, c4 = f & 15;
        const float4 v4 = *(const float4*)(Qb + (size_t)(par + 2 * (qt * BQ + r)) * D_ + c4 * 4);
        __bf16* d = &q_s[r][c4 * 4];
        d[0] = (__bf16)v4.x; d[1] = (__bf16)v4.y; d[2] = (__bf16)v4.z; d[3] = (__bf16)v4.w;
    }

    f32x4 acc[4];
    #pragma unroll
    for (int nt = 0; nt < 4; ++nt) acc[nt] = (f32x4){0.f, 0.f, 0.f, 0.f};
    float m_run[4], l_run[4];
    #pragma unroll
    for (int r = 0; r < 4; ++r) { m_run[r] = 0.f; l_run[r] = 0.f; }  // m init 0: masked zeros exist

    const int q0 = wave * 16;

    for (int kt = 0; kt < NKT; ++kt) {
        __syncthreads();   // previous tile fully consumed
        // ---- stage K tile (row-major bf16) and V tile (transposed, hi/lo bf16)
        #pragma unroll
        for (int i = 0; i < 4; ++i) {
            const int f = (i << 8) + tid;
            const int r = f >> 4, c4 = f & 15;
            const size_t grow = (size_t)(par + 2 * (kt * BK + r)) * D_;
            const float4 kv = *(const float4*)(Kb + grow + c4 * 4);
            const float4 vv = *(const float4*)(Vb + grow + c4 * 4);
            __bf16* kd = &k_s[r][c4 * 4];
            kd[0] = (__bf16)kv.x; kd[1] = (__bf16)kv.y; kd[2] = (__bf16)kv.z; kd[3] = (__bf16)kv.w;
            const float xs[4] = {vv.x, vv.y, vv.z, vv.w};
            #pragma unroll
            for (int c = 0; c < 4; ++c) {
                const float x = xs[c];
                const __bf16 h = (__bf16)x;
                vhi_s[c4 * 4 + c][r] = h;
                vlo_s[c4 * 4 + c][r] = (__bf16)(x - (float)h);
            }
        }
        __syncthreads();

        // ---- S = Q K^T  (raw dot products; scale 1/8 applied at exp time)
        f32x4 sc[4];
        #pragma unroll
        for (int nt = 0; nt < 4; ++nt) sc[nt] = (f32x4){0.f, 0.f, 0.f, 0.f};
        #pragma unroll
        for (int ks = 0; ks < 2; ++ks) {
            const bf16x8 a = *(const bf16x8*)&q_s[q0 + l15][ks * 32 + quad * 8];
            #pragma unroll
            for (int nt = 0; nt < 4; ++nt) {
                const bf16x8 b = *(const bf16x8*)&k_s[nt * 16 + l15][ks * 32 + quad * 8];
                sc[nt] = __builtin_amdgcn_mfma_f32_16x16x32_bf16(a, b, sc[nt], 0, 0, 0);
            }
        }

        // ---- online softmax (rows live in 16-lane quad groups -> shfl_xor 1,2,4,8)
        float m_new[4], alpha[4];
        #pragma unroll
        for (int r = 0; r < 4; ++r) {
            float m0 = fmaxf(fmaxf(sc[0][r], sc[1][r]), fmaxf(sc[2][r], sc[3][r])) * 0.125f;
            #pragma unroll
            for (int off = 1; off < 16; off <<= 1) m0 = fmaxf(m0, __shfl_xor(m0, off));
            m_new[r] = fmaxf(m_run[r], m0);
            alpha[r] = __expf(m_run[r] - m_new[r]);
            m_run[r] = m_new[r];
        }
        float lp[4] = {0.f, 0.f, 0.f, 0.f};
        #pragma unroll
        for (int nt = 0; nt < 4; ++nt) {
            #pragma unroll
            for (int r = 0; r < 4; ++r) {
                const float p = __expf(sc[nt][r] * 0.125f - m_new[r]);
                lp[r] += p;
                p_s[wave][quad * 4 + r][nt * 16 + l15] = (__bf16)p;
            }
            acc[nt][0] *= alpha[0]; acc[nt][1] *= alpha[1];
            acc[nt][2] *= alpha[2]; acc[nt][3] *= alpha[3];
        }
        #pragma unroll
        for (int r = 0; r < 4; ++r) {
            float s = lp[r];
            #pragma unroll
            for (int off = 1; off < 16; off <<= 1) s += __shfl_xor(s, off);
            l_run[r] = l_run[r] * alpha[r] + s;
        }

        // ---- O += P V   (V split hi+lo bf16 to keep value precision ~fp32)
        #pragma unroll
        for (int ks = 0; ks < 2; ++ks) {
            const bf16x8 pa = *(const bf16x8*)&p_s[wave][l15][ks * 32 + quad * 8];
            #pragma unroll
            for (int nt = 0; nt < 4; ++nt) {
                const bf16x8 bhv = *(const bf16x8*)&vhi_s[nt * 16 + l15][ks * 32 + quad * 8];
                acc[nt] = __builtin_amdgcn_mfma_f32_16x16x32_bf16(pa, bhv, acc[nt], 0, 0, 0);
                const bf16x8 blv = *(const bf16x8*)&vlo_s[nt * 16 + l15][ks * 32 + quad * 8];
                acc[nt] = __builtin_amdgcn_mfma_f32_16x16x32_bf16(pa, blv, acc[nt], 0, 0, 0);
            }
        }
    }

    // ---- epilogue: masked-entry correction + normalize
    const float* vs_o = vsum + ((size_t)bh * 2 + (1 - par)) * D_;
    float vso[4];
    #pragma unroll
    for (int nt = 0; nt < 4; ++nt) vso[nt] = vs_o[nt * 16 + l15];
    float wc[4], rz[4];
    #pragma unroll
    for (int r = 0; r < 4; ++r) {
        wc[r] = __expf(-m_run[r]);                       // m_run >= 0 always
        rz[r] = 1.0f / (l_run[r] + 1024.0f * wc[r]);
    }
    #pragma unroll
    for (int nt = 0; nt < 4; ++nt) {
        #pragma unroll
        for (int r = 0; r < 4; ++r) {
            const int qg = par + 2 * (qt * BQ + q0 + quad * 4 + r);
            out[base + (size_t)qg * D_ + nt * 16 + l15] =
                (acc[nt][r] + wc[r] * vso[nt]) * rz[r];
        }
    }
}

extern "C" void kernel_launch(void* const* d_in, const int* in_sizes, int n_in,
                              void* d_out, int out_size, void* d_ws, size_t ws_size,
                              hipStream_t stream) {
    const float* Q = (const float*)d_in[0];
    const float* K = (const float*)d_in[1];
    const float* V = (const float*)d_in[2];
    float* out  = (float*)d_out;
    float* vsum = (float*)d_ws;   // needs 32*2*64*4 = 16 KiB of workspace

    vsum_kernel<<<dim3(B_ * H_), dim3(1024), 0, stream>>>(V, vsum);
    attn_kernel<<<dim3(B_ * H_, 2, SP_ / BQ), dim3(256), 0, stream>>>(Q, K, V, vsum, out);
}

// Round 2
// 130.653 us; speedup vs baseline: 1.6096x; 1.6096x over previous
//
#include <hip/hip_runtime.h>
#include <hip/hip_bf16.h>

// Dilated-mask attention, B=2 H=16 S=2048 D=64, dilation=2.
// Same-parity flash attention with fixed m=0 (scores/8 bounded « fp32 exp
// range), correction out += Vsum_otherparity, Z = l + 1024.

#define B_   2
#define H_   16
#define S_   2048
#define D_   64
#define SP_  1024
#define BQ   64
#define BK   64
#define NKT  (SP_ / BK)
#define LSTR 72     // q/k/v row stride in bf16: 144 B = 9*16 B, b128-aligned

// Q pre-scale: 1/sqrt(64) * log2(e)  ->  p = exp2(QK') = exp(QK/8)
#define QSCALE 0.180336884f

typedef __bf16 bf16x8 __attribute__((ext_vector_type(8)));
typedef float  f32x4  __attribute__((ext_vector_type(4)));

// ---------------- Vsum: vsum[bh][parity][d] = sum_j V[bh][j][d] over parity j
// 256 blocks (bh x 8 chunks of 256 rows), atomicAdd into zeroed workspace.
__global__ __launch_bounds__(256) void vsum_kernel(const float* __restrict__ V,
                                                   float* __restrict__ vsum) {
    const int bh  = blockIdx.x >> 3;
    const int c   = blockIdx.x & 7;
    const int tid = threadIdx.x;
    const int d   = tid & 63;
    const int rq  = tid >> 6;                    // 0..3
    const float* p0 = V + (size_t)bh * S_ * D_ + (size_t)(c * 256 + rq * 64) * D_ + d;
    float se = 0.f, so = 0.f;
    for (int j = 0; j < 64; j += 2) {            // row parity == j&1 (chunk base even)
        se += p0[(size_t)j * D_];
        so += p0[(size_t)(j + 1) * D_];
    }
    __shared__ float red[2][4][64];
    red[0][rq][d] = se;
    red[1][rq][d] = so;
    __syncthreads();
    if (tid < 128) {
        const int p = tid >> 6, dd = tid & 63;
        const float s = red[p][0][dd] + red[p][1][dd] + red[p][2][dd] + red[p][3][dd];
        atomicAdd(&vsum[((size_t)bh * 2 + p) * D_ + dd], s);
    }
}

// ---------------- Main kernel
__global__ __launch_bounds__(256, 4) void attn_kernel(const float* __restrict__ Q,
                                                      const float* __restrict__ K,
                                                      const float* __restrict__ V,
                                                      const float* __restrict__ vsum,
                                                      float* __restrict__ out) {
    const int bh  = blockIdx.x;
    const int par = blockIdx.y;
    const int qt  = blockIdx.z;
    const int tid  = threadIdx.x;
    const int lane = tid & 63;
    const int wave = tid >> 6;       // wave w owns query rows [16w, 16w+16)
    const int l15  = lane & 15;
    const int quad = lane >> 4;

    __shared__ __align__(16) __bf16 q_s[BQ][LSTR];
    __shared__ __align__(16) __bf16 k_s[BK][LSTR];
    __shared__ __align__(16) __bf16 v_s[D_][LSTR];     // V^T: [d][key]
    // P strip per wave, swizzled: P[m][n] stored at [m][(n + 16*(m>>2)) & 63]
    // -> 16B-aligned rows, conflict-free scalar writes, single b128 A-frag reads.
    __shared__ __align__(16) __bf16 p_s[4][16][64];

    const size_t base = (size_t)bh * S_ * D_;
    const float* Qb = Q + base;
    const float* Kb = K + base;
    const float* Vb = V + base;

    // ---- stage Q tile: rows par + 2*(qt*64 + r), pre-scaled, b128 writes
    #pragma unroll
    for (int i = 0; i < 2; ++i) {
        const int f = (i << 8) + tid;            // 0..511
        const int r = f >> 3, c8 = f & 7;
        const float* src = Qb + (size_t)(par + 2 * (qt * BQ + r)) * D_ + c8 * 8;
        const float4 a = *(const float4*)src;
        const float4 b = *(const float4*)(src + 4);
        bf16x8 w;
        w[0] = (__bf16)(a.x * QSCALE); w[1] = (__bf16)(a.y * QSCALE);
        w[2] = (__bf16)(a.z * QSCALE); w[3] = (__bf16)(a.w * QSCALE);
        w[4] = (__bf16)(b.x * QSCALE); w[5] = (__bf16)(b.y * QSCALE);
        w[6] = (__bf16)(b.z * QSCALE); w[7] = (__bf16)(b.w * QSCALE);
        *(bf16x8*)&q_s[r][c8 * 8] = w;
    }

    f32x4 acc[4];
    #pragma unroll
    for (int nt = 0; nt < 4; ++nt) acc[nt] = (f32x4){0.f, 0.f, 0.f, 0.f};
    float l_acc[4] = {0.f, 0.f, 0.f, 0.f};

    const int q0 = wave * 16;

    for (int kt = 0; kt < NKT; ++kt) {
        __syncthreads();   // previous tile fully consumed

        // ---- K tile: row-major bf16, b128 writes
        #pragma unroll
        for (int i = 0; i < 2; ++i) {
            const int f = (i << 8) + tid;
            const int r = f >> 3, c8 = f & 7;
            const float* src = Kb + (size_t)(par + 2 * (kt * BK + r)) * D_ + c8 * 8;
            const float4 a = *(const float4*)src;
            const float4 b = *(const float4*)(src + 4);
            bf16x8 w;
            w[0] = (__bf16)a.x; w[1] = (__bf16)a.y; w[2] = (__bf16)a.z; w[3] = (__bf16)a.w;
            w[4] = (__bf16)b.x; w[5] = (__bf16)b.y; w[6] = (__bf16)b.z; w[7] = (__bf16)b.w;
            *(bf16x8*)&k_s[r][c8 * 8] = w;
        }
        // ---- V tile transposed: lane d reads column d of 8 rows (coalesced),
        //      packs bf16x8, one b128 write per pass (stride-144B = conflict-free)
        #pragma unroll
        for (int i = 0; i < 2; ++i) {
            const int r0 = (wave + 4 * i) << 3;                  // 0,8,...,56
            const float* src = Vb + (size_t)(par + 2 * (kt * BK + r0)) * D_ + lane;
            bf16x8 w;
            #pragma unroll
            for (int j = 0; j < 8; ++j)
                w[j] = (__bf16)src[(size_t)(2 * j) * D_];
            *(bf16x8*)&v_s[lane][r0] = w;
        }
        __syncthreads();

        // ---- S' = (Q*QSCALE) K^T
        f32x4 sc[4];
        #pragma unroll
        for (int nt = 0; nt < 4; ++nt) sc[nt] = (f32x4){0.f, 0.f, 0.f, 0.f};
        #pragma unroll
        for (int ks = 0; ks < 2; ++ks) {
            const bf16x8 a = *(const bf16x8*)&q_s[q0 + l15][ks * 32 + quad * 8];
            #pragma unroll
            for (int nt = 0; nt < 4; ++nt) {
                const bf16x8 b = *(const bf16x8*)&k_s[nt * 16 + l15][ks * 32 + quad * 8];
                sc[nt] = __builtin_amdgcn_mfma_f32_16x16x32_bf16(a, b, sc[nt], 0, 0, 0);
            }
        }

        // ---- p = exp2(s'), accumulate per-lane l, write P strip (swizzled)
        #pragma unroll
        for (int nt = 0; nt < 4; ++nt) {
            const int colw = ((((nt + quad) & 3) << 4) + l15);
            #pragma unroll
            for (int r = 0; r < 4; ++r) {
                const float p = exp2f(sc[nt][r]);
                l_acc[r] += p;
                p_s[wave][quad * 4 + r][colw] = (__bf16)p;
            }
        }

        // ---- O += P V
        #pragma unroll
        for (int ks = 0; ks < 2; ++ks) {
            const int col0 = ((((2 * ks + (quad >> 1) + (l15 >> 2)) & 3) << 4)
                              + ((quad & 1) << 3));
            const bf16x8 pa = *(const bf16x8*)&p_s[wave][l15][col0];
            #pragma unroll
            for (int nt = 0; nt < 4; ++nt) {
                const bf16x8 bv = *(const bf16x8*)&v_s[nt * 16 + l15][ks * 32 + quad * 8];
                acc[nt] = __builtin_amdgcn_mfma_f32_16x16x32_bf16(pa, bv, acc[nt], 0, 0, 0);
            }
        }
    }

    // ---- epilogue: single l reduction, masked-key correction (weight 1 each)
    float rz[4];
    #pragma unroll
    for (int r = 0; r < 4; ++r) {
        float s = l_acc[r];
        #pragma unroll
        for (int off = 1; off < 16; off <<= 1) s += __shfl_xor(s, off);
        rz[r] = 1.0f / (s + 1024.0f);
    }
    const float* vs_o = vsum + ((size_t)bh * 2 + (1 - par)) * D_;
    #pragma unroll
    for (int nt = 0; nt < 4; ++nt) {
        const float vso = vs_o[nt * 16 + l15];
        #pragma unroll
        for (int r = 0; r < 4; ++r) {
            const int qg = par + 2 * (qt * BQ + q0 + quad * 4 + r);
            out[base + (size_t)qg * D_ + nt * 16 + l15] = (acc[nt][r] + vso) * rz[r];
        }
    }
}

extern "C" void kernel_launch(void* const* d_in, const int* in_sizes, int n_in,
                              void* d_out, int out_size, void* d_ws, size_t ws_size,
                              hipStream_t stream) {
    const float* Q = (const float*)d_in[0];
    const float* K = (const float*)d_in[1];
    const float* V = (const float*)d_in[2];
    float* out  = (float*)d_out;
    float* vsum = (float*)d_ws;   // 32*2*64 f32 = 16 KiB

    hipMemsetAsync(vsum, 0, (size_t)B_ * H_ * 2 * D_ * sizeof(float), stream);
    vsum_kernel<<<dim3(B_ * H_ * 8), dim3(256), 0, stream>>>(V, vsum);
    attn_kernel<<<dim3(B_ * H_, 2, SP_ / BQ), dim3(256), 0, stream>>>(Q, K, V, vsum, out);
}